// Round 11
// baseline (144.255 us; speedup 1.0000x reference)
//
#include <hip/hip_runtime.h>

#define N_ROWS 8192
#define N_LBL  1024
#define KMAX   64

constexpr float C_COS_M  = (float)0.8775825618903728;   // cos(0.5)
constexpr float C_SIN_M  = (float)0.479425538604203;    // sin(0.5)
constexpr float C_THRESH = (float)-0.8775825618903728;  // cos(pi-0.5)
constexpr float C_MM     = (float)0.2397127693021015;   // sin(pi-0.5)*0.5
constexpr float C_ALPHA  = 0.1f;
constexpr float C_VALID  = 0.8f;
constexpr float C_K2E    = (float)(1.0 / (0.07 * 0.6931471805599453)); // 1/(T*ln2)
constexpr float C_LN2    = 0.6931471805599453f;

typedef short s16x8 __attribute__((ext_vector_type(8)));
typedef float f32x4 __attribute__((ext_vector_type(4)));

__device__ __forceinline__ unsigned f2bf(float f) {
    unsigned u = __float_as_uint(f);
    return (u + 0x7fffu + ((u >> 16) & 1u)) >> 16;   // RNE to bf16
}
__device__ __forceinline__ float bflo(unsigned u) { return __uint_as_float(u << 16); }
__device__ __forceinline__ float bfhi(unsigned u) { return __uint_as_float(u & 0xffff0000u); }

// async 16B global->LDS (lands at wave-uniform base + lane*16)
__device__ __forceinline__ void gl_lds16(const unsigned* g, void* lds) {
    __builtin_amdgcn_global_load_lds(
        (const __attribute__((address_space(1))) unsigned*)g,
        (__attribute__((address_space(3))) unsigned*)lds, 16, 0, 0);
}

// ---- K1: row-normalize -> packed bf16; scatter rows into fixed-stride label buckets ----
__global__ void k_norm(const float* __restrict__ f1, const float* __restrict__ f2,
                       const int* __restrict__ labels,
                       unsigned* __restrict__ f1n, unsigned* __restrict__ f2n,
                       int* __restrict__ hist, unsigned short* __restrict__ bucket,
                       float* __restrict__ out) {
    if (blockIdx.x == 0 && threadIdx.x == 0) out[0] = 0.f;
    int b = blockIdx.x * 4 + (threadIdx.x >> 6);
    int l = threadIdx.x & 63;
    int row = (b < N_ROWS) ? b : (b - N_ROWS);
    const float* src = (b < N_ROWS) ? f1 : f2;
    unsigned* dst = (b < N_ROWS) ? f1n : f2n;
    float2 v = ((const float2*)(src + row * 128))[l];
    float ss = v.x * v.x + v.y * v.y;
    #pragma unroll
    for (int k = 1; k < 64; k <<= 1) ss += __shfl_xor(ss, k);
    float inv = 1.0f / fmaxf(sqrtf(ss), 1e-12f);
    dst[row * 64 + l] = f2bf(v.x * inv) | (f2bf(v.y * inv) << 16);
    if (b < N_ROWS && l == 0) {
        int lab = labels[row];
        int p = atomicAdd(&hist[lab], 1);           // hist pre-zeroed by memset
        if (p < KMAX) bucket[lab * KMAX + p] = (unsigned short)row;
    }
}

// ---- K2: positive pairs from buckets (4 rows/block, one wave per row) ----
__global__ __launch_bounds__(256) void k_passA(const unsigned* __restrict__ f1n,
                                               const unsigned* __restrict__ f2n,
                                               const int* __restrict__ labels,
                                               const int* __restrict__ hist,
                                               const unsigned short* __restrict__ bucket,
                                               float* __restrict__ rt,
                                               float* __restrict__ row_sim,
                                               int* __restrict__ rowcnt,
                                               float* __restrict__ simlist) {
    int tid = threadIdx.x;
    int lane = tid & 63;
    int i = blockIdx.x * 4 + (tid >> 6);
    int g = lane >> 4, sl = lane & 15;
    uint4 a = ((const uint4*)(f1n + i * 64))[sl];
    float a0 = bflo(a.x), a1 = bfhi(a.x), a2 = bflo(a.y), a3 = bfhi(a.y);
    float a4 = bflo(a.z), a5 = bfhi(a.z), a6 = bflo(a.w), a7 = bfhi(a.w);
    int lab = labels[i];
    int cnt = hist[lab];
    int cntc = cnt < KMAX ? cnt : KMAX;
    float rs_sim = 0.f, rs_fp = 0.f;
    for (int e0 = 0; e0 < cntc; e0 += 4) {
        int e = e0 + g;
        bool val = e < cntc;
        int j = bucket[lab * KMAX + (val ? e : 0)];
        uint4 b = ((const uint4*)(f2n + j * 64))[sl];
        float p = a0 * bflo(b.x) + a1 * bfhi(b.x) + a2 * bflo(b.y) + a3 * bfhi(b.y)
                + a4 * bflo(b.z) + a5 * bfhi(b.z) + a6 * bflo(b.w) + a7 * bfhi(b.w);
        p += __shfl_xor(p, 1);
        p += __shfl_xor(p, 2);
        p += __shfl_xor(p, 4);
        p += __shfl_xor(p, 8);
        float s = fminf(1.f, fmaxf(-1.f, p));
        float ctm = s * C_COS_M - sqrtf(fmaxf(0.f, 1.f - s * s)) * C_SIN_M;
        float fpv = (s > C_THRESH) ? ctm : (s - C_MM);
        if (val) {
            rs_sim += s;
            rs_fp += fpv;
            if (sl == 0) simlist[i * KMAX + e] = s;
        }
    }
    rs_sim += __shfl_xor(rs_sim, 16); rs_sim += __shfl_xor(rs_sim, 32);
    rs_fp  += __shfl_xor(rs_fp, 16);  rs_fp  += __shfl_xor(rs_fp, 32);
    if (lane == 0) {
        rt[i] = rs_fp / (float)cnt;
        row_sim[i] = rs_sim;
        rowcnt[i] = cnt;
    }
}

// ---- K3: t (and implicitly weight_valid) ----
__global__ void k_finalize(const float* __restrict__ row_sim, const int* __restrict__ hist,
                           float* __restrict__ tw) {
    int t = threadIdx.x;
    float ssum = 0.f, scnt = 0.f;
    if (t < N_LBL) { float h = (float)hist[t]; scnt = h * h; }
    #pragma unroll
    for (int p = 0; p < 8; ++p) ssum += row_sim[p * 1024 + t];
    #pragma unroll
    for (int k = 1; k < 64; k <<= 1) {
        ssum += __shfl_xor(ssum, k);
        scnt += __shfl_xor(scnt, k);
    }
    __shared__ float sa[16], sb[16];
    if ((t & 63) == 0) { sa[t >> 6] = ssum; sb[t >> 6] = scnt; }
    __syncthreads();
    if (t == 0) {
        float s1 = 0.f, s2 = 0.f;
        #pragma unroll
        for (int w = 0; w < 16; ++w) { s1 += sa[w]; s2 += sb[w]; }
        tw[0] = C_ALPHA * s1 / s2;
    }
}

// ---- K4: dense pass; A via LDS-DMA, B via pinned inline-asm global loads (barrier-free loop) ----
#define MFMA_(A, B, C) __builtin_amdgcn_mfma_f32_16x16x32_bf16((A), (B), (C), 0, 0, 0)

// pinned 16B load: issue order fixed by asm volatile; compiler cannot sink it
#define LD16(dst, addr, OFF) \
    asm volatile("global_load_dwordx4 %0, %1, off offset:" #OFF : "=v"(dst) : "v"(addr))

// load one 16-col B tile (4 x dwordx4, offsets 0/64/128/192 B) into named regs
#define LOADASM(bp, ct_) { const unsigned* p_ = bb + (ct_) * 1024;         \
    LD16(bp##0, p_, 0); LD16(bp##1, p_, 64);                               \
    LD16(bp##2, p_, 128); LD16(bp##3, p_, 192); }

// counted wait + scheduling fence (rule #18: MFMA may hoist past asm waitcnt)
#define WAITV(n_) asm volatile("s_waitcnt vmcnt(" #n_ ")" ::: "memory")
#define SBAR      __builtin_amdgcn_sched_barrier(0)

#define EPI1(sv, rtvv, lnpv, WVC) {                                        \
    float s_ = (sv);                                                       \
    float u_ = C_K2E * s_;                                                 \
    float arg_ = (s_ > (rtvv)) ? u_ * (tval + s_) : u_;                    \
    float e_ = __builtin_amdgcn_exp2f(arg_);                               \
    if (WVC) { float cz_ = fmaxf(s_, 0.f); e_ = e_ * (cz_ * cz_ + 1.f); }  \
    (lnpv) += e_; }

#define TILE(bp, WVC) {                                                    \
    f32x4 a0_ = (f32x4){0.f, 0.f, 0.f, 0.f};                               \
    f32x4 a1_ = (f32x4){0.f, 0.f, 0.f, 0.f};                               \
    a0_ = MFMA_(af00, bp##0, a0_); a1_ = MFMA_(af10, bp##0, a1_);          \
    a0_ = MFMA_(af01, bp##1, a0_); a1_ = MFMA_(af11, bp##1, a1_);          \
    a0_ = MFMA_(af02, bp##2, a0_); a1_ = MFMA_(af12, bp##2, a1_);          \
    a0_ = MFMA_(af03, bp##3, a0_); a1_ = MFMA_(af13, bp##3, a1_);          \
    EPI1(a0_[0], rtv00, lnp00, WVC); EPI1(a0_[1], rtv01, lnp01, WVC);      \
    EPI1(a0_[2], rtv02, lnp02, WVC); EPI1(a0_[3], rtv03, lnp03, WVC);      \
    EPI1(a1_[0], rtv10, lnp10, WVC); EPI1(a1_[1], rtv11, lnp11, WVC);      \
    EPI1(a1_[2], rtv12, lnp12, WVC); EPI1(a1_[3], rtv13, lnp13, WVC); }

// barrier-free steady state: issue tile ct+1 (4 loads), wait vmcnt(4) -> tile ct
// resident (oldest 4 complete), consume. Tile 0 was issued pre-barrier (drained).
#define RUNLOOP(WVC) {                                                     \
    _Pragma("unroll 1")                                                    \
    for (int ct = 0; ct < 16; ct += 2) {                                   \
        LOADASM(b1_, ct + 1);                                              \
        WAITV(4); SBAR;                                                    \
        TILE(b0_, WVC);                                                    \
        if (ct + 2 < 16) { LOADASM(b0_, ct + 2); WAITV(4); }               \
        else             { WAITV(0); }                                     \
        SBAR;                                                              \
        TILE(b1_, WVC);                                                    \
    } }

#define STORE1(lnpv, mt, r) { float v_ = (lnpv);                           \
    v_ += __shfl_xor(v_, 1); v_ += __shfl_xor(v_, 2);                      \
    v_ += __shfl_xor(v_, 4); v_ += __shfl_xor(v_, 8);                      \
    if (l15 == 0)                                                          \
        lnacc2[slice * N_ROWS + rowbase + wr * 32 + (mt) * 16 + quad * 4 + (r)] = v_; }

__global__ __launch_bounds__(512, 4) void k_passB(const unsigned* __restrict__ f1n,
                                                  const unsigned* __restrict__ f2n,
                                                  const float* __restrict__ rt,
                                                  const float* __restrict__ tw,
                                                  float* __restrict__ lnacc2) {
    __shared__ __align__(16) unsigned char ldsA[32768];
    const int tid = threadIdx.x;
    const int wave = tid >> 6, lane = tid & 63;
    const int wr = wave >> 1, wc = wave & 1;     // wave tile: 32 rows x 256 cols
    const int quad = lane >> 4, l15 = lane & 15;
    const int rowbase = blockIdx.x * 128;
    const float tval = tw[0];
    const bool wv = (tval > C_VALID);

    // stage A tile (128 rows, 32 KB), XOR-swizzled on the global-source side
    {
        const int srow = tid >> 4;                        // 0..31
        const int sq   = (tid & 15) ^ (srow & 15);
        const unsigned* gA = f1n + rowbase * 64 + srow * 64 + sq * 4;
        const int loff = wave * 1024;
        #pragma unroll
        for (int it = 0; it < 4; ++it)
            gl_lds16(gA + it * 2048, ldsA + loff + it * 8192);
    }

    // B fragment base: col = y*512 + wc*256 + ct*16 + l15; addr = col*64 + ks*16 + quad*4
    const unsigned* bb = f2n + (blockIdx.y * 512 + wc * 256 + l15) * 64 + quad * 4;

    s16x8 b0_0, b0_1, b0_2, b0_3;
    s16x8 b1_0, b1_1, b1_2, b1_3;
    LOADASM(b0_, 0);   // tile 0 in flight alongside A staging; drained at the barrier

    const int rbase = rowbase + wr * 32 + quad * 4;
    float rtv00 = rt[rbase + 0],  rtv01 = rt[rbase + 1];
    float rtv02 = rt[rbase + 2],  rtv03 = rt[rbase + 3];
    float rtv10 = rt[rbase + 16], rtv11 = rt[rbase + 17];
    float rtv12 = rt[rbase + 18], rtv13 = rt[rbase + 19];

    __syncthreads();   // the only barrier: A (and tile-0 loads) resident, vmcnt drained

    // A fragments for the whole K=128 into named VGPRs (8 x ds_read_b128)
    const unsigned char* pA0 = ldsA + (wr * 32 + l15) * 256;
    const unsigned char* pA1 = pA0 + 16 * 256;
    s16x8 af00 = *((const s16x8*)(pA0 + (((0 * 4 + quad) ^ l15) << 4)));
    s16x8 af01 = *((const s16x8*)(pA0 + (((1 * 4 + quad) ^ l15) << 4)));
    s16x8 af02 = *((const s16x8*)(pA0 + (((2 * 4 + quad) ^ l15) << 4)));
    s16x8 af03 = *((const s16x8*)(pA0 + (((3 * 4 + quad) ^ l15) << 4)));
    s16x8 af10 = *((const s16x8*)(pA1 + (((0 * 4 + quad) ^ l15) << 4)));
    s16x8 af11 = *((const s16x8*)(pA1 + (((1 * 4 + quad) ^ l15) << 4)));
    s16x8 af12 = *((const s16x8*)(pA1 + (((2 * 4 + quad) ^ l15) << 4)));
    s16x8 af13 = *((const s16x8*)(pA1 + (((3 * 4 + quad) ^ l15) << 4)));

    float lnp00 = 0.f, lnp01 = 0.f, lnp02 = 0.f, lnp03 = 0.f;
    float lnp10 = 0.f, lnp11 = 0.f, lnp12 = 0.f, lnp13 = 0.f;

    if (wv) { RUNLOOP(1); } else { RUNLOOP(0); }

    // per-row partial sums: non-atomic slice store (32 slices, fully overwritten)
    const int slice = blockIdx.y * 2 + wc;
    STORE1(lnp00, 0, 0); STORE1(lnp01, 0, 1); STORE1(lnp02, 0, 2); STORE1(lnp03, 0, 3);
    STORE1(lnp10, 1, 0); STORE1(lnp11, 1, 1); STORE1(lnp12, 1, 2); STORE1(lnp13, 1, 3);
}

// ---- K5: positive correction + per-row loss + fused final reduce ----
__global__ void k_lossC(const float* __restrict__ simlist, const int* __restrict__ rowcnt,
                        const float* __restrict__ rt, const float* __restrict__ tw,
                        const float* __restrict__ lnacc2, float* __restrict__ out) {
    int t = threadIdx.x;
    int sub = t >> 3, sl = t & 7;
    int i = blockIdx.x * 32 + sub;
    int cnt = rowcnt[i];
    if (cnt > KMAX) cnt = KMAX;
    float tval = tw[0];
    bool wv = (tval > C_VALID);
    float rti = rt[i];
    float lp = 0.f, den = 0.f;
    for (int e = sl; e < cnt; e += 8) {
        float s = simlist[i * KMAX + e];
        // what k_passB added for this (pos) entry:
        float sh = (s > rti) ? s * (tval + s) : s;
        float en = __builtin_amdgcn_exp2f(C_K2E * sh);
        // true positive contribution:
        float ctm = s * C_COS_M - sqrtf(fmaxf(0.f, 1.f - s * s)) * C_SIN_M;
        float fp = (s > C_THRESH) ? ctm : (s - C_MM);
        float ep = __builtin_amdgcn_exp2f(C_K2E * fp);
        if (wv) {
            float cz = fmaxf(s, 0.f);
            en *= cz * cz + 1.f;
            float d = 1.f - s;
            ep *= d * d + 1.f;
        }
        den -= en;
        lp += ep;
    }
    // dense-pass partials: 32 slices, 4 per lane
    float lnsum = 0.f;
    #pragma unroll
    for (int p = 0; p < 4; ++p) lnsum += lnacc2[(sl + p * 8) * N_ROWS + i];
    #pragma unroll
    for (int k = 1; k < 8; k <<= 1) {
        den += __shfl_xor(den, k);
        lp += __shfl_xor(lp, k);
        lnsum += __shfl_xor(lnsum, k);
    }
    float ln = lnsum + den;
    float rl = (__builtin_amdgcn_logf(lp + ln) - __builtin_amdgcn_logf(lp)) * C_LN2;
    // all 8 sub-lanes hold rl; sum the wave's 8 rows (each counted once)
    rl += __shfl_xor(rl, 8);
    rl += __shfl_xor(rl, 16);
    rl += __shfl_xor(rl, 32);
    __shared__ float sa[4];
    if ((t & 63) == 0) sa[t >> 6] = rl;
    __syncthreads();
    if (t == 0)
        atomicAdd(out, (sa[0] + sa[1] + sa[2] + sa[3]) * (1.0f / (float)N_ROWS));
}

extern "C" void kernel_launch(void* const* d_in, const int* in_sizes, int n_in,
                              void* d_out, int out_size, void* d_ws, size_t ws_size,
                              hipStream_t stream) {
    (void)in_sizes; (void)n_in; (void)out_size; (void)ws_size;
    const float* f1 = (const float*)d_in[0];
    const float* f2 = (const float*)d_in[1];
    const int* labels = (const int*)d_in[2];
    float* out = (float*)d_out;
    char* ws = (char*)d_ws;

    // ws layout (bytes); only hist needs pre-zero (atomic counters)
    unsigned* f1n          = (unsigned*)(ws + 0);              // 2 MB  bf16-packed
    unsigned* f2n          = (unsigned*)(ws + 2097152);        // 2 MB
    float* simlist         = (float*)(ws + 4194304);           // 2 MB (64 sims/row cap)
    float* rt              = (float*)(ws + 6291456);           // 32 KB
    float* row_sim         = (float*)(ws + 6324224);           // 32 KB
    int* rowcnt            = (int*)(ws + 6356992);             // 32 KB
    float* lnacc2          = (float*)(ws + 6389760);           // 1 MB (32 slices x 8192)
    unsigned short* bucket = (unsigned short*)(ws + 7438336);  // 128 KB (1024 x 64 x u16)
    float* tw              = (float*)(ws + 7569408);           // 4 B
    int* hist              = (int*)(ws + 7569472);             // 4 KB  -- zeroed

    hipMemsetAsync(hist, 0, 4096, stream);

    k_norm<<<dim3(4096), dim3(256), 0, stream>>>(f1, f2, labels, f1n, f2n, hist, bucket, out);
    k_passA<<<dim3(2048), dim3(256), 0, stream>>>(f1n, f2n, labels, hist, bucket,
                                                  rt, row_sim, rowcnt, simlist);
    k_finalize<<<dim3(1), dim3(1024), 0, stream>>>(row_sim, hist, tw);
    k_passB<<<dim3(64, 16), dim3(512), 0, stream>>>(f1n, f2n, rt, tw, lnacc2);
    k_lossC<<<dim3(256), dim3(256), 0, stream>>>(simlist, rowcnt, rt, tw, lnacc2, out);
}

// Round 12
// 143.810 us; speedup vs baseline: 1.0031x; 1.0031x over previous
//
#include <hip/hip_runtime.h>

#define N_ROWS 8192
#define N_LBL  1024
#define KMAX   64

constexpr float C_COS_M  = (float)0.8775825618903728;   // cos(0.5)
constexpr float C_SIN_M  = (float)0.479425538604203;    // sin(0.5)
constexpr float C_THRESH = (float)-0.8775825618903728;  // cos(pi-0.5)
constexpr float C_MM     = (float)0.2397127693021015;   // sin(pi-0.5)*0.5
constexpr float C_ALPHA  = 0.1f;
constexpr float C_VALID  = 0.8f;
constexpr float C_K2E    = (float)(1.0 / (0.07 * 0.6931471805599453)); // 1/(T*ln2)
constexpr float C_LN2    = 0.6931471805599453f;

typedef short s16x8 __attribute__((ext_vector_type(8)));
typedef float f32x4 __attribute__((ext_vector_type(4)));

__device__ __forceinline__ unsigned f2bf(float f) {
    unsigned u = __float_as_uint(f);
    return (u + 0x7fffu + ((u >> 16) & 1u)) >> 16;   // RNE to bf16
}
__device__ __forceinline__ float bflo(unsigned u) { return __uint_as_float(u << 16); }
__device__ __forceinline__ float bfhi(unsigned u) { return __uint_as_float(u & 0xffff0000u); }

// async 16B global->LDS (lands at wave-uniform base + lane*16)
__device__ __forceinline__ void gl_lds16(const unsigned* g, void* lds) {
    __builtin_amdgcn_global_load_lds(
        (const __attribute__((address_space(1))) unsigned*)g,
        (__attribute__((address_space(3))) unsigned*)lds, 16, 0, 0);
}

// ---- K1: row-normalize -> packed bf16; scatter rows into fixed-stride label buckets ----
__global__ void k_norm(const float* __restrict__ f1, const float* __restrict__ f2,
                       const int* __restrict__ labels,
                       unsigned* __restrict__ f1n, unsigned* __restrict__ f2n,
                       int* __restrict__ hist, unsigned short* __restrict__ bucket,
                       float* __restrict__ out) {
    if (blockIdx.x == 0 && threadIdx.x == 0) out[0] = 0.f;
    int b = blockIdx.x * 4 + (threadIdx.x >> 6);
    int l = threadIdx.x & 63;
    int row = (b < N_ROWS) ? b : (b - N_ROWS);
    const float* src = (b < N_ROWS) ? f1 : f2;
    unsigned* dst = (b < N_ROWS) ? f1n : f2n;
    float2 v = ((const float2*)(src + row * 128))[l];
    float ss = v.x * v.x + v.y * v.y;
    #pragma unroll
    for (int k = 1; k < 64; k <<= 1) ss += __shfl_xor(ss, k);
    float inv = 1.0f / fmaxf(sqrtf(ss), 1e-12f);
    dst[row * 64 + l] = f2bf(v.x * inv) | (f2bf(v.y * inv) << 16);
    if (b < N_ROWS && l == 0) {
        int lab = labels[row];
        int p = atomicAdd(&hist[lab], 1);           // hist pre-zeroed by memset
        if (p < KMAX) bucket[lab * KMAX + p] = (unsigned short)row;
    }
}

// ---- K2: positive pairs from buckets (4 rows/block, one wave per row) ----
__global__ __launch_bounds__(256) void k_passA(const unsigned* __restrict__ f1n,
                                               const unsigned* __restrict__ f2n,
                                               const int* __restrict__ labels,
                                               const int* __restrict__ hist,
                                               const unsigned short* __restrict__ bucket,
                                               float* __restrict__ rt,
                                               float* __restrict__ row_sim,
                                               int* __restrict__ rowcnt,
                                               float* __restrict__ simlist) {
    int tid = threadIdx.x;
    int lane = tid & 63;
    int i = blockIdx.x * 4 + (tid >> 6);
    int g = lane >> 4, sl = lane & 15;
    uint4 a = ((const uint4*)(f1n + i * 64))[sl];
    float a0 = bflo(a.x), a1 = bfhi(a.x), a2 = bflo(a.y), a3 = bfhi(a.y);
    float a4 = bflo(a.z), a5 = bfhi(a.z), a6 = bflo(a.w), a7 = bfhi(a.w);
    int lab = labels[i];
    int cnt = hist[lab];
    int cntc = cnt < KMAX ? cnt : KMAX;
    float rs_sim = 0.f, rs_fp = 0.f;
    for (int e0 = 0; e0 < cntc; e0 += 4) {
        int e = e0 + g;
        bool val = e < cntc;
        int j = bucket[lab * KMAX + (val ? e : 0)];
        uint4 b = ((const uint4*)(f2n + j * 64))[sl];
        float p = a0 * bflo(b.x) + a1 * bfhi(b.x) + a2 * bflo(b.y) + a3 * bfhi(b.y)
                + a4 * bflo(b.z) + a5 * bfhi(b.z) + a6 * bflo(b.w) + a7 * bfhi(b.w);
        p += __shfl_xor(p, 1);
        p += __shfl_xor(p, 2);
        p += __shfl_xor(p, 4);
        p += __shfl_xor(p, 8);
        float s = fminf(1.f, fmaxf(-1.f, p));
        float ctm = s * C_COS_M - sqrtf(fmaxf(0.f, 1.f - s * s)) * C_SIN_M;
        float fpv = (s > C_THRESH) ? ctm : (s - C_MM);
        if (val) {
            rs_sim += s;
            rs_fp += fpv;
            if (sl == 0) simlist[i * KMAX + e] = s;
        }
    }
    rs_sim += __shfl_xor(rs_sim, 16); rs_sim += __shfl_xor(rs_sim, 32);
    rs_fp  += __shfl_xor(rs_fp, 16);  rs_fp  += __shfl_xor(rs_fp, 32);
    if (lane == 0) {
        rt[i] = rs_fp / (float)cnt;
        row_sim[i] = rs_sim;
        rowcnt[i] = cnt;
    }
}

// ---- K3: t (and implicitly weight_valid) ----
__global__ void k_finalize(const float* __restrict__ row_sim, const int* __restrict__ hist,
                           float* __restrict__ tw) {
    int t = threadIdx.x;
    float ssum = 0.f, scnt = 0.f;
    if (t < N_LBL) { float h = (float)hist[t]; scnt = h * h; }
    #pragma unroll
    for (int p = 0; p < 8; ++p) ssum += row_sim[p * 1024 + t];
    #pragma unroll
    for (int k = 1; k < 64; k <<= 1) {
        ssum += __shfl_xor(ssum, k);
        scnt += __shfl_xor(scnt, k);
    }
    __shared__ float sa[16], sb[16];
    if ((t & 63) == 0) { sa[t >> 6] = ssum; sb[t >> 6] = scnt; }
    __syncthreads();
    if (t == 0) {
        float s1 = 0.f, s2 = 0.f;
        #pragma unroll
        for (int w = 0; w < 16; ++w) { s1 += sa[w]; s2 += sb[w]; }
        tw[0] = C_ALPHA * s1 / s2;
    }
}

// ---- K4: dense pass; A via LDS-DMA, B via pinned inline-asm global loads (barrier-free loop) ----
// __launch_bounds__(512, 2): under new-toolchain (CUDA min-blocks) semantics = 2 blocks/CU
// -> 16 waves/CU -> 128-VGPR cap. Under waves/EU semantics = 2 waves/EU, even laxer.
// (512, 4) was read as 4 blocks/CU = 8 waves/SIMD -> hard 64-VGPR cap -> remat/spill (r6-r11).
#define MFMA_(A, B, C) __builtin_amdgcn_mfma_f32_16x16x32_bf16((A), (B), (C), 0, 0, 0)

// pinned 16B load: issue order fixed by asm volatile; compiler cannot sink it
#define LD16(dst, addr, OFF) \
    asm volatile("global_load_dwordx4 %0, %1, off offset:" #OFF : "=v"(dst) : "v"(addr))

// load one 16-col B tile (4 x dwordx4, offsets 0/64/128/192 B) into named regs
#define LOADASM(bp, ct_) { const unsigned* p_ = bb + (ct_) * 1024;         \
    LD16(bp##0, p_, 0); LD16(bp##1, p_, 64);                               \
    LD16(bp##2, p_, 128); LD16(bp##3, p_, 192); }

// counted wait + scheduling fence (rule #18: MFMA may hoist past asm waitcnt)
#define WAITV(n_) asm volatile("s_waitcnt vmcnt(" #n_ ")" ::: "memory")
#define SBAR      __builtin_amdgcn_sched_barrier(0)

#define EPI1(sv, rtvv, lnpv, WVC) {                                        \
    float s_ = (sv);                                                       \
    float u_ = C_K2E * s_;                                                 \
    float arg_ = (s_ > (rtvv)) ? u_ * (tval + s_) : u_;                    \
    float e_ = __builtin_amdgcn_exp2f(arg_);                               \
    if (WVC) { float cz_ = fmaxf(s_, 0.f); e_ = e_ * (cz_ * cz_ + 1.f); }  \
    (lnpv) += e_; }

#define TILE(bp, WVC) {                                                    \
    f32x4 a0_ = (f32x4){0.f, 0.f, 0.f, 0.f};                               \
    f32x4 a1_ = (f32x4){0.f, 0.f, 0.f, 0.f};                               \
    a0_ = MFMA_(af00, bp##0, a0_); a1_ = MFMA_(af10, bp##0, a1_);          \
    a0_ = MFMA_(af01, bp##1, a0_); a1_ = MFMA_(af11, bp##1, a1_);          \
    a0_ = MFMA_(af02, bp##2, a0_); a1_ = MFMA_(af12, bp##2, a1_);          \
    a0_ = MFMA_(af03, bp##3, a0_); a1_ = MFMA_(af13, bp##3, a1_);          \
    EPI1(a0_[0], rtv00, lnp00, WVC); EPI1(a0_[1], rtv01, lnp01, WVC);      \
    EPI1(a0_[2], rtv02, lnp02, WVC); EPI1(a0_[3], rtv03, lnp03, WVC);      \
    EPI1(a1_[0], rtv10, lnp10, WVC); EPI1(a1_[1], rtv11, lnp11, WVC);      \
    EPI1(a1_[2], rtv12, lnp12, WVC); EPI1(a1_[3], rtv13, lnp13, WVC); }

// barrier-free steady state: issue tile ct+1 (4 loads), wait vmcnt(4) -> tile ct
// resident (oldest 4 complete), consume. Tile 0 was issued pre-barrier (drained).
#define RUNLOOP(WVC) {                                                     \
    _Pragma("unroll 1")                                                    \
    for (int ct = 0; ct < 16; ct += 2) {                                   \
        LOADASM(b1_, ct + 1);                                              \
        WAITV(4); SBAR;                                                    \
        TILE(b0_, WVC);                                                    \
        if (ct + 2 < 16) { LOADASM(b0_, ct + 2); WAITV(4); }               \
        else             { WAITV(0); }                                     \
        SBAR;                                                              \
        TILE(b1_, WVC);                                                    \
    } }

#define STORE1(lnpv, mt, r) { float v_ = (lnpv);                           \
    v_ += __shfl_xor(v_, 1); v_ += __shfl_xor(v_, 2);                      \
    v_ += __shfl_xor(v_, 4); v_ += __shfl_xor(v_, 8);                      \
    if (l15 == 0)                                                          \
        lnacc2[slice * N_ROWS + rowbase + wr * 32 + (mt) * 16 + quad * 4 + (r)] = v_; }

__global__ __launch_bounds__(512, 2) void k_passB(const unsigned* __restrict__ f1n,
                                                  const unsigned* __restrict__ f2n,
                                                  const float* __restrict__ rt,
                                                  const float* __restrict__ tw,
                                                  float* __restrict__ lnacc2) {
    __shared__ __align__(16) unsigned char ldsA[32768];
    const int tid = threadIdx.x;
    const int wave = tid >> 6, lane = tid & 63;
    const int wr = wave >> 1, wc = wave & 1;     // wave tile: 32 rows x 256 cols
    const int quad = lane >> 4, l15 = lane & 15;
    const int rowbase = blockIdx.x * 128;
    const float tval = tw[0];
    const bool wv = (tval > C_VALID);

    // stage A tile (128 rows, 32 KB), XOR-swizzled on the global-source side
    {
        const int srow = tid >> 4;                        // 0..31
        const int sq   = (tid & 15) ^ (srow & 15);
        const unsigned* gA = f1n + rowbase * 64 + srow * 64 + sq * 4;
        const int loff = wave * 1024;
        #pragma unroll
        for (int it = 0; it < 4; ++it)
            gl_lds16(gA + it * 2048, ldsA + loff + it * 8192);
    }

    // B fragment base: col = y*512 + wc*256 + ct*16 + l15; addr = col*64 + ks*16 + quad*4
    const unsigned* bb = f2n + (blockIdx.y * 512 + wc * 256 + l15) * 64 + quad * 4;

    s16x8 b0_0, b0_1, b0_2, b0_3;
    s16x8 b1_0, b1_1, b1_2, b1_3;
    LOADASM(b0_, 0);   // tile 0 in flight alongside A staging; drained at the barrier

    const int rbase = rowbase + wr * 32 + quad * 4;
    float rtv00 = rt[rbase + 0],  rtv01 = rt[rbase + 1];
    float rtv02 = rt[rbase + 2],  rtv03 = rt[rbase + 3];
    float rtv10 = rt[rbase + 16], rtv11 = rt[rbase + 17];
    float rtv12 = rt[rbase + 18], rtv13 = rt[rbase + 19];

    __syncthreads();   // the only barrier: A (and tile-0 loads) resident, vmcnt drained

    // A fragments for the whole K=128 into named VGPRs (8 x ds_read_b128)
    const unsigned char* pA0 = ldsA + (wr * 32 + l15) * 256;
    const unsigned char* pA1 = pA0 + 16 * 256;
    s16x8 af00 = *((const s16x8*)(pA0 + (((0 * 4 + quad) ^ l15) << 4)));
    s16x8 af01 = *((const s16x8*)(pA0 + (((1 * 4 + quad) ^ l15) << 4)));
    s16x8 af02 = *((const s16x8*)(pA0 + (((2 * 4 + quad) ^ l15) << 4)));
    s16x8 af03 = *((const s16x8*)(pA0 + (((3 * 4 + quad) ^ l15) << 4)));
    s16x8 af10 = *((const s16x8*)(pA1 + (((0 * 4 + quad) ^ l15) << 4)));
    s16x8 af11 = *((const s16x8*)(pA1 + (((1 * 4 + quad) ^ l15) << 4)));
    s16x8 af12 = *((const s16x8*)(pA1 + (((2 * 4 + quad) ^ l15) << 4)));
    s16x8 af13 = *((const s16x8*)(pA1 + (((3 * 4 + quad) ^ l15) << 4)));

    float lnp00 = 0.f, lnp01 = 0.f, lnp02 = 0.f, lnp03 = 0.f;
    float lnp10 = 0.f, lnp11 = 0.f, lnp12 = 0.f, lnp13 = 0.f;

    if (wv) { RUNLOOP(1); } else { RUNLOOP(0); }

    // per-row partial sums: non-atomic slice store (32 slices, fully overwritten)
    const int slice = blockIdx.y * 2 + wc;
    STORE1(lnp00, 0, 0); STORE1(lnp01, 0, 1); STORE1(lnp02, 0, 2); STORE1(lnp03, 0, 3);
    STORE1(lnp10, 1, 0); STORE1(lnp11, 1, 1); STORE1(lnp12, 1, 2); STORE1(lnp13, 1, 3);
}

// ---- K5: positive correction + per-row loss + fused final reduce ----
__global__ void k_lossC(const float* __restrict__ simlist, const int* __restrict__ rowcnt,
                        const float* __restrict__ rt, const float* __restrict__ tw,
                        const float* __restrict__ lnacc2, float* __restrict__ out) {
    int t = threadIdx.x;
    int sub = t >> 3, sl = t & 7;
    int i = blockIdx.x * 32 + sub;
    int cnt = rowcnt[i];
    if (cnt > KMAX) cnt = KMAX;
    float tval = tw[0];
    bool wv = (tval > C_VALID);
    float rti = rt[i];
    float lp = 0.f, den = 0.f;
    for (int e = sl; e < cnt; e += 8) {
        float s = simlist[i * KMAX + e];
        // what k_passB added for this (pos) entry:
        float sh = (s > rti) ? s * (tval + s) : s;
        float en = __builtin_amdgcn_exp2f(C_K2E * sh);
        // true positive contribution:
        float ctm = s * C_COS_M - sqrtf(fmaxf(0.f, 1.f - s * s)) * C_SIN_M;
        float fp = (s > C_THRESH) ? ctm : (s - C_MM);
        float ep = __builtin_amdgcn_exp2f(C_K2E * fp);
        if (wv) {
            float cz = fmaxf(s, 0.f);
            en *= cz * cz + 1.f;
            float d = 1.f - s;
            ep *= d * d + 1.f;
        }
        den -= en;
        lp += ep;
    }
    // dense-pass partials: 32 slices, 4 per lane
    float lnsum = 0.f;
    #pragma unroll
    for (int p = 0; p < 4; ++p) lnsum += lnacc2[(sl + p * 8) * N_ROWS + i];
    #pragma unroll
    for (int k = 1; k < 8; k <<= 1) {
        den += __shfl_xor(den, k);
        lp += __shfl_xor(lp, k);
        lnsum += __shfl_xor(lnsum, k);
    }
    float ln = lnsum + den;
    float rl = (__builtin_amdgcn_logf(lp + ln) - __builtin_amdgcn_logf(lp)) * C_LN2;
    // all 8 sub-lanes hold rl; sum the wave's 8 rows (each counted once)
    rl += __shfl_xor(rl, 8);
    rl += __shfl_xor(rl, 16);
    rl += __shfl_xor(rl, 32);
    __shared__ float sa[4];
    if ((t & 63) == 0) sa[t >> 6] = rl;
    __syncthreads();
    if (t == 0)
        atomicAdd(out, (sa[0] + sa[1] + sa[2] + sa[3]) * (1.0f / (float)N_ROWS));
}

extern "C" void kernel_launch(void* const* d_in, const int* in_sizes, int n_in,
                              void* d_out, int out_size, void* d_ws, size_t ws_size,
                              hipStream_t stream) {
    (void)in_sizes; (void)n_in; (void)out_size; (void)ws_size;
    const float* f1 = (const float*)d_in[0];
    const float* f2 = (const float*)d_in[1];
    const int* labels = (const int*)d_in[2];
    float* out = (float*)d_out;
    char* ws = (char*)d_ws;

    // ws layout (bytes); only hist needs pre-zero (atomic counters)
    unsigned* f1n          = (unsigned*)(ws + 0);              // 2 MB  bf16-packed
    unsigned* f2n          = (unsigned*)(ws + 2097152);        // 2 MB
    float* simlist         = (float*)(ws + 4194304);           // 2 MB (64 sims/row cap)
    float* rt              = (float*)(ws + 6291456);           // 32 KB
    float* row_sim         = (float*)(ws + 6324224);           // 32 KB
    int* rowcnt            = (int*)(ws + 6356992);             // 32 KB
    float* lnacc2          = (float*)(ws + 6389760);           // 1 MB (32 slices x 8192)
    unsigned short* bucket = (unsigned short*)(ws + 7438336);  // 128 KB (1024 x 64 x u16)
    float* tw              = (float*)(ws + 7569408);           // 4 B
    int* hist              = (int*)(ws + 7569472);             // 4 KB  -- zeroed

    hipMemsetAsync(hist, 0, 4096, stream);

    k_norm<<<dim3(4096), dim3(256), 0, stream>>>(f1, f2, labels, f1n, f2n, hist, bucket, out);
    k_passA<<<dim3(2048), dim3(256), 0, stream>>>(f1n, f2n, labels, hist, bucket,
                                                  rt, row_sim, rowcnt, simlist);
    k_finalize<<<dim3(1), dim3(1024), 0, stream>>>(row_sim, hist, tw);
    k_passB<<<dim3(64, 16), dim3(512), 0, stream>>>(f1n, f2n, rt, tw, lnacc2);
    k_lossC<<<dim3(256), dim3(256), 0, stream>>>(simlist, rowcnt, rt, tw, lnacc2, out);
}

// Round 13
// 114.792 us; speedup vs baseline: 1.2567x; 1.2528x over previous
//
#include <hip/hip_runtime.h>

#define N_ROWS 8192
#define N_LBL  1024
#define KMAX   64

constexpr float C_COS_M  = (float)0.8775825618903728;   // cos(0.5)
constexpr float C_SIN_M  = (float)0.479425538604203;    // sin(0.5)
constexpr float C_THRESH = (float)-0.8775825618903728;  // cos(pi-0.5)
constexpr float C_MM     = (float)0.2397127693021015;   // sin(pi-0.5)*0.5
constexpr float C_ALPHA  = 0.1f;
constexpr float C_VALID  = 0.8f;
constexpr float C_K2E    = (float)(1.0 / (0.07 * 0.6931471805599453)); // 1/(T*ln2)
constexpr float C_LN2    = 0.6931471805599453f;

typedef short s16x8 __attribute__((ext_vector_type(8)));
typedef float f32x4 __attribute__((ext_vector_type(4)));

__device__ __forceinline__ unsigned f2bf(float f) {
    unsigned u = __float_as_uint(f);
    return (u + 0x7fffu + ((u >> 16) & 1u)) >> 16;   // RNE to bf16
}
__device__ __forceinline__ float bflo(unsigned u) { return __uint_as_float(u << 16); }
__device__ __forceinline__ float bfhi(unsigned u) { return __uint_as_float(u & 0xffff0000u); }

// async 16B global->LDS (lands at wave-uniform base + lane*16)
__device__ __forceinline__ void gl_lds16(const unsigned* g, void* lds) {
    __builtin_amdgcn_global_load_lds(
        (const __attribute__((address_space(1))) unsigned*)g,
        (__attribute__((address_space(3))) unsigned*)lds, 16, 0, 0);
}

// ---- K1: row-normalize -> packed bf16; scatter rows into fixed-stride label buckets ----
__global__ void k_norm(const float* __restrict__ f1, const float* __restrict__ f2,
                       const int* __restrict__ labels,
                       unsigned* __restrict__ f1n, unsigned* __restrict__ f2n,
                       int* __restrict__ hist, unsigned short* __restrict__ bucket,
                       float* __restrict__ out) {
    if (blockIdx.x == 0 && threadIdx.x == 0) out[0] = 0.f;
    int b = blockIdx.x * 4 + (threadIdx.x >> 6);
    int l = threadIdx.x & 63;
    int row = (b < N_ROWS) ? b : (b - N_ROWS);
    const float* src = (b < N_ROWS) ? f1 : f2;
    unsigned* dst = (b < N_ROWS) ? f1n : f2n;
    float2 v = ((const float2*)(src + row * 128))[l];
    float ss = v.x * v.x + v.y * v.y;
    #pragma unroll
    for (int k = 1; k < 64; k <<= 1) ss += __shfl_xor(ss, k);
    float inv = 1.0f / fmaxf(sqrtf(ss), 1e-12f);
    dst[row * 64 + l] = f2bf(v.x * inv) | (f2bf(v.y * inv) << 16);
    if (b < N_ROWS && l == 0) {
        int lab = labels[row];
        int p = atomicAdd(&hist[lab], 1);           // hist pre-zeroed by memset
        if (p < KMAX) bucket[lab * KMAX + p] = (unsigned short)row;
    }
}

// ---- K2: positive pairs from buckets (4 rows/block, one wave per row) ----
__global__ __launch_bounds__(256) void k_passA(const unsigned* __restrict__ f1n,
                                               const unsigned* __restrict__ f2n,
                                               const int* __restrict__ labels,
                                               const int* __restrict__ hist,
                                               const unsigned short* __restrict__ bucket,
                                               float* __restrict__ rt,
                                               float* __restrict__ row_sim,
                                               int* __restrict__ rowcnt,
                                               float* __restrict__ simlist) {
    int tid = threadIdx.x;
    int lane = tid & 63;
    int i = blockIdx.x * 4 + (tid >> 6);
    int g = lane >> 4, sl = lane & 15;
    uint4 a = ((const uint4*)(f1n + i * 64))[sl];
    float a0 = bflo(a.x), a1 = bfhi(a.x), a2 = bflo(a.y), a3 = bfhi(a.y);
    float a4 = bflo(a.z), a5 = bfhi(a.z), a6 = bflo(a.w), a7 = bfhi(a.w);
    int lab = labels[i];
    int cnt = hist[lab];
    int cntc = cnt < KMAX ? cnt : KMAX;
    float rs_sim = 0.f, rs_fp = 0.f;
    for (int e0 = 0; e0 < cntc; e0 += 4) {
        int e = e0 + g;
        bool val = e < cntc;
        int j = bucket[lab * KMAX + (val ? e : 0)];
        uint4 b = ((const uint4*)(f2n + j * 64))[sl];
        float p = a0 * bflo(b.x) + a1 * bfhi(b.x) + a2 * bflo(b.y) + a3 * bfhi(b.y)
                + a4 * bflo(b.z) + a5 * bfhi(b.z) + a6 * bflo(b.w) + a7 * bfhi(b.w);
        p += __shfl_xor(p, 1);
        p += __shfl_xor(p, 2);
        p += __shfl_xor(p, 4);
        p += __shfl_xor(p, 8);
        float s = fminf(1.f, fmaxf(-1.f, p));
        float ctm = s * C_COS_M - sqrtf(fmaxf(0.f, 1.f - s * s)) * C_SIN_M;
        float fpv = (s > C_THRESH) ? ctm : (s - C_MM);
        if (val) {
            rs_sim += s;
            rs_fp += fpv;
            if (sl == 0) simlist[i * KMAX + e] = s;
        }
    }
    rs_sim += __shfl_xor(rs_sim, 16); rs_sim += __shfl_xor(rs_sim, 32);
    rs_fp  += __shfl_xor(rs_fp, 16);  rs_fp  += __shfl_xor(rs_fp, 32);
    if (lane == 0) {
        rt[i] = rs_fp / (float)cnt;
        row_sim[i] = rs_sim;
        rowcnt[i] = cnt;
    }
}

// ---- K3: t (and implicitly weight_valid) ----
__global__ void k_finalize(const float* __restrict__ row_sim, const int* __restrict__ hist,
                           float* __restrict__ tw) {
    int t = threadIdx.x;
    float ssum = 0.f, scnt = 0.f;
    if (t < N_LBL) { float h = (float)hist[t]; scnt = h * h; }
    #pragma unroll
    for (int p = 0; p < 8; ++p) ssum += row_sim[p * 1024 + t];
    #pragma unroll
    for (int k = 1; k < 64; k <<= 1) {
        ssum += __shfl_xor(ssum, k);
        scnt += __shfl_xor(scnt, k);
    }
    __shared__ float sa[16], sb[16];
    if ((t & 63) == 0) { sa[t >> 6] = ssum; sb[t >> 6] = scnt; }
    __syncthreads();
    if (t == 0) {
        float s1 = 0.f, s2 = 0.f;
        #pragma unroll
        for (int w = 0; w < 16; ++w) { s1 += sa[w]; s2 += sb[w]; }
        tw[0] = C_ALPHA * s1 / s2;
    }
}

// ---- K4: dense pass; A + B async-DMA'd to LDS; B = 3-buffer ring of 2-tile (16KB) phases ----
// 8 barrier phases (was 16): each phase stages 2 K-tiles (2 DMA instr/wave), waits
// vmcnt(2) for the pair issued 2 phases ago (~1200cy cover), consumes 2 tiles.
#define MFMA_(A, B, C) __builtin_amdgcn_mfma_f32_16x16x32_bf16((A), (B), (C), 0, 0, 0)

#define WAITV(n_) asm volatile("s_waitcnt vmcnt(" #n_ ")" ::: "memory")

// stage phase-pair pp (tiles 2pp, 2pp+1) into ring buffer bf_ (16 KB = 2 x 8 KB)
#define STAGE2(pp_, bf_) {                                                  \
    gl_lds16(gBsrc + (pp_) * 2048,                                          \
             ldsAll + 32768 + (bf_) * 16384 + wave * 1024);                 \
    gl_lds16(gBsrc + (pp_) * 2048 + 1024,                                   \
             ldsAll + 32768 + (bf_) * 16384 + 8192 + wave * 1024); }

// read this wave's 4 B fragments (swizzled) from sub-tile j of ring buffer bf_
#define LOADBF(bf_, j_) { const unsigned char* pb_ =                        \
        ldsAll + 32768 + (bf_) * 16384 + (j_) * 8192 + bcol * 256;          \
    bf0 = *((const s16x8*)(pb_ + (((0 * 4 + quad) ^ l15) << 4)));           \
    bf1 = *((const s16x8*)(pb_ + (((1 * 4 + quad) ^ l15) << 4)));           \
    bf2 = *((const s16x8*)(pb_ + (((2 * 4 + quad) ^ l15) << 4)));           \
    bf3 = *((const s16x8*)(pb_ + (((3 * 4 + quad) ^ l15) << 4))); }

#define EPI1(sv, rtvv, lnpv, WVC) {                                         \
    float s_ = (sv);                                                        \
    float u_ = C_K2E * s_;                                                  \
    float arg_ = (s_ > (rtvv)) ? u_ * (tval + s_) : u_;                     \
    float e_ = __builtin_amdgcn_exp2f(arg_);                                \
    if (WVC) { float cz_ = fmaxf(s_, 0.f); e_ = e_ * (cz_ * cz_ + 1.f); }   \
    (lnpv) += e_; }

#define TILE(WVC) {                                                         \
    f32x4 a0_ = (f32x4){0.f, 0.f, 0.f, 0.f};                                \
    f32x4 a1_ = (f32x4){0.f, 0.f, 0.f, 0.f};                                \
    a0_ = MFMA_(af00, bf0, a0_); a1_ = MFMA_(af10, bf0, a1_);               \
    a0_ = MFMA_(af01, bf1, a0_); a1_ = MFMA_(af11, bf1, a1_);               \
    a0_ = MFMA_(af02, bf2, a0_); a1_ = MFMA_(af12, bf2, a1_);               \
    a0_ = MFMA_(af03, bf3, a0_); a1_ = MFMA_(af13, bf3, a1_);               \
    EPI1(a0_[0], rtv00, lnp00, WVC); EPI1(a0_[1], rtv01, lnp01, WVC);       \
    EPI1(a0_[2], rtv02, lnp02, WVC); EPI1(a0_[3], rtv03, lnp03, WVC);       \
    EPI1(a1_[0], rtv10, lnp10, WVC); EPI1(a1_[1], rtv11, lnp11, WVC);       \
    EPI1(a1_[2], rtv12, lnp12, WVC); EPI1(a1_[3], rtv13, lnp13, WVC); }

// one phase: wait own pair -> barrier (all waves' pair landed; prev readers done)
// -> stage pair pp+2 (WAR-safe: overwrites buffer last read in phase pp-1) -> consume
#define PH(pp_, bf_, wn_, dostage_, sbf_, WVC) {                            \
    WAITV(wn_);                                                             \
    __builtin_amdgcn_s_barrier();                                           \
    if (dostage_) STAGE2((pp_) + 2, sbf_);                                  \
    { s16x8 bf0, bf1, bf2, bf3; LOADBF(bf_, 0); TILE(WVC); }                \
    { s16x8 bf0, bf1, bf2, bf3; LOADBF(bf_, 1); TILE(WVC); } }

// pair pp lives in buffer pp%3: 0,1,2,0,1,2,0,1
#define RUNLOOP(WVC) {                                                      \
    PH(0, 0, 2, 1, 2, WVC)                                                  \
    PH(1, 1, 2, 1, 0, WVC)                                                  \
    PH(2, 2, 2, 1, 1, WVC)                                                  \
    PH(3, 0, 2, 1, 2, WVC)                                                  \
    PH(4, 1, 2, 1, 0, WVC)                                                  \
    PH(5, 2, 2, 1, 1, WVC)                                                  \
    PH(6, 0, 2, 0, 0, WVC)                                                  \
    PH(7, 1, 0, 0, 0, WVC) }

#define STORE1(lnpv, mt, r) { float v_ = (lnpv);                            \
    v_ += __shfl_xor(v_, 1); v_ += __shfl_xor(v_, 2);                       \
    v_ += __shfl_xor(v_, 4); v_ += __shfl_xor(v_, 8);                       \
    if (l15 == 0)                                                           \
        lnacc2[slice * N_ROWS + rowbase + wr * 32 + (mt) * 16 + quad * 4 + (r)] = v_; }

__global__ __launch_bounds__(512) void k_passB(const unsigned* __restrict__ f1n,
                                               const unsigned* __restrict__ f2n,
                                               const float* __restrict__ rt,
                                               const float* __restrict__ tw,
                                               float* __restrict__ lnacc2) {
    __shared__ __align__(16) unsigned char ldsAll[81920];  // A: 0..32K, B ring: 3 x 16K
    const int tid = threadIdx.x;
    const int wave = tid >> 6, lane = tid & 63;
    const int wr = wave >> 1, wc = wave & 1;     // wave tile: 32 rows x 256 cols
    const int quad = lane >> 4, l15 = lane & 15;
    const int rowbase = blockIdx.x * 128;
    const float tval = tw[0];
    const bool wv = (tval > C_VALID);

    // stage A tile (128 rows, 32 KB), XOR-swizzled on the global-source side
    {
        const int srow = tid >> 4;                        // 0..31
        const int sq   = (tid & 15) ^ (srow & 15);
        const unsigned* gA = f1n + rowbase * 64 + srow * 64 + sq * 4;
        const int loff = wave * 1024;
        #pragma unroll
        for (int it = 0; it < 4; ++it)
            gl_lds16(gA + it * 2048, ldsAll + loff + it * 8192);
    }

    // per-thread B DMA source (same XOR involution as A, pre-swizzled on global side)
    const int col16 = tid >> 4;
    const int ch    = tid & 15;
    const unsigned* gBsrc = f2n
        + (blockIdx.y * 512 + ((col16 >> 4) << 8) + (col16 & 15)) * 64
        + ((ch ^ (col16 & 15)) << 2);

    STAGE2(0, 0);   // prime pairs 0,1 of the ring alongside A
    STAGE2(1, 1);

    const int rbase = rowbase + wr * 32 + quad * 4;
    float rtv00 = rt[rbase + 0],  rtv01 = rt[rbase + 1];
    float rtv02 = rt[rbase + 2],  rtv03 = rt[rbase + 3];
    float rtv10 = rt[rbase + 16], rtv11 = rt[rbase + 17];
    float rtv12 = rt[rbase + 18], rtv13 = rt[rbase + 19];

    __syncthreads();   // full drain: A + pairs 0,1 resident

    // A fragments for the whole K=128 into named VGPRs (8 x ds_read_b128)
    const unsigned char* pA0 = ldsAll + (wr * 32 + l15) * 256;
    const unsigned char* pA1 = pA0 + 16 * 256;
    s16x8 af00 = *((const s16x8*)(pA0 + (((0 * 4 + quad) ^ l15) << 4)));
    s16x8 af01 = *((const s16x8*)(pA0 + (((1 * 4 + quad) ^ l15) << 4)));
    s16x8 af02 = *((const s16x8*)(pA0 + (((2 * 4 + quad) ^ l15) << 4)));
    s16x8 af03 = *((const s16x8*)(pA0 + (((3 * 4 + quad) ^ l15) << 4)));
    s16x8 af10 = *((const s16x8*)(pA1 + (((0 * 4 + quad) ^ l15) << 4)));
    s16x8 af11 = *((const s16x8*)(pA1 + (((1 * 4 + quad) ^ l15) << 4)));
    s16x8 af12 = *((const s16x8*)(pA1 + (((2 * 4 + quad) ^ l15) << 4)));
    s16x8 af13 = *((const s16x8*)(pA1 + (((3 * 4 + quad) ^ l15) << 4)));

    const int bcol = wc * 16 + l15;    // this wave's column slot in each 32-col sub-tile

    float lnp00 = 0.f, lnp01 = 0.f, lnp02 = 0.f, lnp03 = 0.f;
    float lnp10 = 0.f, lnp11 = 0.f, lnp12 = 0.f, lnp13 = 0.f;

    if (wv) { RUNLOOP(1); } else { RUNLOOP(0); }

    // per-row partial sums: non-atomic slice store (32 slices, fully overwritten)
    const int slice = blockIdx.y * 2 + wc;
    STORE1(lnp00, 0, 0); STORE1(lnp01, 0, 1); STORE1(lnp02, 0, 2); STORE1(lnp03, 0, 3);
    STORE1(lnp10, 1, 0); STORE1(lnp11, 1, 1); STORE1(lnp12, 1, 2); STORE1(lnp13, 1, 3);
}

// ---- K5: positive correction + per-row loss + fused final reduce ----
__global__ void k_lossC(const float* __restrict__ simlist, const int* __restrict__ rowcnt,
                        const float* __restrict__ rt, const float* __restrict__ tw,
                        const float* __restrict__ lnacc2, float* __restrict__ out) {
    int t = threadIdx.x;
    int sub = t >> 3, sl = t & 7;
    int i = blockIdx.x * 32 + sub;
    int cnt = rowcnt[i];
    if (cnt > KMAX) cnt = KMAX;
    float tval = tw[0];
    bool wv = (tval > C_VALID);
    float rti = rt[i];
    float lp = 0.f, den = 0.f;
    for (int e = sl; e < cnt; e += 8) {
        float s = simlist[i * KMAX + e];
        // what k_passB added for this (pos) entry:
        float sh = (s > rti) ? s * (tval + s) : s;
        float en = __builtin_amdgcn_exp2f(C_K2E * sh);
        // true positive contribution:
        float ctm = s * C_COS_M - sqrtf(fmaxf(0.f, 1.f - s * s)) * C_SIN_M;
        float fp = (s > C_THRESH) ? ctm : (s - C_MM);
        float ep = __builtin_amdgcn_exp2f(C_K2E * fp);
        if (wv) {
            float cz = fmaxf(s, 0.f);
            en *= cz * cz + 1.f;
            float d = 1.f - s;
            ep *= d * d + 1.f;
        }
        den -= en;
        lp += ep;
    }
    // dense-pass partials: 32 slices, 4 per lane
    float lnsum = 0.f;
    #pragma unroll
    for (int p = 0; p < 4; ++p) lnsum += lnacc2[(sl + p * 8) * N_ROWS + i];
    #pragma unroll
    for (int k = 1; k < 8; k <<= 1) {
        den += __shfl_xor(den, k);
        lp += __shfl_xor(lp, k);
        lnsum += __shfl_xor(lnsum, k);
    }
    float ln = lnsum + den;
    float rl = (__builtin_amdgcn_logf(lp + ln) - __builtin_amdgcn_logf(lp)) * C_LN2;
    // all 8 sub-lanes hold rl; sum the wave's 8 rows (each counted once)
    rl += __shfl_xor(rl, 8);
    rl += __shfl_xor(rl, 16);
    rl += __shfl_xor(rl, 32);
    __shared__ float sa[4];
    if ((t & 63) == 0) sa[t >> 6] = rl;
    __syncthreads();
    if (t == 0)
        atomicAdd(out, (sa[0] + sa[1] + sa[2] + sa[3]) * (1.0f / (float)N_ROWS));
}

extern "C" void kernel_launch(void* const* d_in, const int* in_sizes, int n_in,
                              void* d_out, int out_size, void* d_ws, size_t ws_size,
                              hipStream_t stream) {
    (void)in_sizes; (void)n_in; (void)out_size; (void)ws_size;
    const float* f1 = (const float*)d_in[0];
    const float* f2 = (const float*)d_in[1];
    const int* labels = (const int*)d_in[2];
    float* out = (float*)d_out;
    char* ws = (char*)d_ws;

    // ws layout (bytes); only hist needs pre-zero (atomic counters)
    unsigned* f1n          = (unsigned*)(ws + 0);              // 2 MB  bf16-packed
    unsigned* f2n          = (unsigned*)(ws + 2097152);        // 2 MB
    float* simlist         = (float*)(ws + 4194304);           // 2 MB (64 sims/row cap)
    float* rt              = (float*)(ws + 6291456);           // 32 KB
    float* row_sim         = (float*)(ws + 6324224);           // 32 KB
    int* rowcnt            = (int*)(ws + 6356992);             // 32 KB
    float* lnacc2          = (float*)(ws + 6389760);           // 1 MB (32 slices x 8192)
    unsigned short* bucket = (unsigned short*)(ws + 7438336);  // 128 KB (1024 x 64 x u16)
    float* tw              = (float*)(ws + 7569408);           // 4 B
    int* hist              = (int*)(ws + 7569472);             // 4 KB  -- zeroed

    hipMemsetAsync(hist, 0, 4096, stream);

    k_norm<<<dim3(4096), dim3(256), 0, stream>>>(f1, f2, labels, f1n, f2n, hist, bucket, out);
    k_passA<<<dim3(2048), dim3(256), 0, stream>>>(f1n, f2n, labels, hist, bucket,
                                                  rt, row_sim, rowcnt, simlist);
    k_finalize<<<dim3(1), dim3(1024), 0, stream>>>(row_sim, hist, tw);
    k_passB<<<dim3(64, 16), dim3(512), 0, stream>>>(f1n, f2n, rt, tw, lnacc2);
    k_lossC<<<dim3(256), dim3(256), 0, stream>>>(simlist, rowcnt, rt, tw, lnacc2, out);
}

// Round 14
// 108.397 us; speedup vs baseline: 1.3308x; 1.0590x over previous
//
#include <hip/hip_runtime.h>

#define N_ROWS 8192
#define N_LBL  1024
#define KMAX   64

constexpr float C_COS_M  = (float)0.8775825618903728;   // cos(0.5)
constexpr float C_SIN_M  = (float)0.479425538604203;    // sin(0.5)
constexpr float C_THRESH = (float)-0.8775825618903728;  // cos(pi-0.5)
constexpr float C_MM     = (float)0.2397127693021015;   // sin(pi-0.5)*0.5
constexpr float C_ALPHA  = 0.1f;
constexpr float C_VALID  = 0.8f;
constexpr float C_K2E    = (float)(1.0 / (0.07 * 0.6931471805599453)); // 1/(T*ln2)
constexpr float C_LN2    = 0.6931471805599453f;

typedef short s16x8 __attribute__((ext_vector_type(8)));
typedef float f32x4 __attribute__((ext_vector_type(4)));

__device__ __forceinline__ unsigned f2bf(float f) {
    unsigned u = __float_as_uint(f);
    return (u + 0x7fffu + ((u >> 16) & 1u)) >> 16;   // RNE to bf16
}
__device__ __forceinline__ float bflo(unsigned u) { return __uint_as_float(u << 16); }
__device__ __forceinline__ float bfhi(unsigned u) { return __uint_as_float(u & 0xffff0000u); }

// async 16B global->LDS (lands at wave-uniform base + lane*16)
__device__ __forceinline__ void gl_lds16(const unsigned* g, void* lds) {
    __builtin_amdgcn_global_load_lds(
        (const __attribute__((address_space(1))) unsigned*)g,
        (__attribute__((address_space(3))) unsigned*)lds, 16, 0, 0);
}

// ---- K1: row-normalize -> packed bf16; scatter rows into fixed-stride label buckets ----
__global__ void k_norm(const float* __restrict__ f1, const float* __restrict__ f2,
                       const int* __restrict__ labels,
                       unsigned* __restrict__ f1n, unsigned* __restrict__ f2n,
                       int* __restrict__ hist, unsigned short* __restrict__ bucket,
                       float* __restrict__ out) {
    if (blockIdx.x == 0 && threadIdx.x == 0) out[0] = 0.f;
    int b = blockIdx.x * 4 + (threadIdx.x >> 6);
    int l = threadIdx.x & 63;
    int row = (b < N_ROWS) ? b : (b - N_ROWS);
    const float* src = (b < N_ROWS) ? f1 : f2;
    unsigned* dst = (b < N_ROWS) ? f1n : f2n;
    float2 v = ((const float2*)(src + row * 128))[l];
    float ss = v.x * v.x + v.y * v.y;
    #pragma unroll
    for (int k = 1; k < 64; k <<= 1) ss += __shfl_xor(ss, k);
    float inv = 1.0f / fmaxf(sqrtf(ss), 1e-12f);
    dst[row * 64 + l] = f2bf(v.x * inv) | (f2bf(v.y * inv) << 16);
    if (b < N_ROWS && l == 0) {
        int lab = labels[row];
        int p = atomicAdd(&hist[lab], 1);           // hist pre-zeroed by memset
        if (p < KMAX) bucket[lab * KMAX + p] = (unsigned short)row;
    }
}

// ---- K2: positive pairs from buckets (4 rows/block, one wave per row) ----
__global__ __launch_bounds__(256) void k_passA(const unsigned* __restrict__ f1n,
                                               const unsigned* __restrict__ f2n,
                                               const int* __restrict__ labels,
                                               const int* __restrict__ hist,
                                               const unsigned short* __restrict__ bucket,
                                               float* __restrict__ rt,
                                               float* __restrict__ row_sim,
                                               int* __restrict__ rowcnt,
                                               float* __restrict__ simlist) {
    int tid = threadIdx.x;
    int lane = tid & 63;
    int i = blockIdx.x * 4 + (tid >> 6);
    int g = lane >> 4, sl = lane & 15;
    uint4 a = ((const uint4*)(f1n + i * 64))[sl];
    float a0 = bflo(a.x), a1 = bfhi(a.x), a2 = bflo(a.y), a3 = bfhi(a.y);
    float a4 = bflo(a.z), a5 = bfhi(a.z), a6 = bflo(a.w), a7 = bfhi(a.w);
    int lab = labels[i];
    int cnt = hist[lab];
    int cntc = cnt < KMAX ? cnt : KMAX;
    float rs_sim = 0.f, rs_fp = 0.f;
    for (int e0 = 0; e0 < cntc; e0 += 4) {
        int e = e0 + g;
        bool val = e < cntc;
        int j = bucket[lab * KMAX + (val ? e : 0)];
        uint4 b = ((const uint4*)(f2n + j * 64))[sl];
        float p = a0 * bflo(b.x) + a1 * bfhi(b.x) + a2 * bflo(b.y) + a3 * bfhi(b.y)
                + a4 * bflo(b.z) + a5 * bfhi(b.z) + a6 * bflo(b.w) + a7 * bfhi(b.w);
        p += __shfl_xor(p, 1);
        p += __shfl_xor(p, 2);
        p += __shfl_xor(p, 4);
        p += __shfl_xor(p, 8);
        float s = fminf(1.f, fmaxf(-1.f, p));
        float ctm = s * C_COS_M - sqrtf(fmaxf(0.f, 1.f - s * s)) * C_SIN_M;
        float fpv = (s > C_THRESH) ? ctm : (s - C_MM);
        if (val) {
            rs_sim += s;
            rs_fp += fpv;
            if (sl == 0) simlist[i * KMAX + e] = s;
        }
    }
    rs_sim += __shfl_xor(rs_sim, 16); rs_sim += __shfl_xor(rs_sim, 32);
    rs_fp  += __shfl_xor(rs_fp, 16);  rs_fp  += __shfl_xor(rs_fp, 32);
    if (lane == 0) {
        rt[i] = rs_fp / (float)cnt;
        row_sim[i] = rs_sim;
        rowcnt[i] = cnt;
    }
}

// ---- K3: t (and implicitly weight_valid) ----
__global__ void k_finalize(const float* __restrict__ row_sim, const int* __restrict__ hist,
                           float* __restrict__ tw) {
    int t = threadIdx.x;
    float ssum = 0.f, scnt = 0.f;
    if (t < N_LBL) { float h = (float)hist[t]; scnt = h * h; }
    #pragma unroll
    for (int p = 0; p < 8; ++p) ssum += row_sim[p * 1024 + t];
    #pragma unroll
    for (int k = 1; k < 64; k <<= 1) {
        ssum += __shfl_xor(ssum, k);
        scnt += __shfl_xor(scnt, k);
    }
    __shared__ float sa[16], sb[16];
    if ((t & 63) == 0) { sa[t >> 6] = ssum; sb[t >> 6] = scnt; }
    __syncthreads();
    if (t == 0) {
        float s1 = 0.f, s2 = 0.f;
        #pragma unroll
        for (int w = 0; w < 16; ++w) { s1 += sa[w]; s2 += sb[w]; }
        tw[0] = C_ALPHA * s1 / s2;
    }
}

// ---- K4: dense pass; A + B async-DMA'd to LDS; B = 4-buffer ring, counted vmcnt ----
#define MFMA_(A, B, C) __builtin_amdgcn_mfma_f32_16x16x32_bf16((A), (B), (C), 0, 0, 0)

// counted wait: leave newer DMAs in flight across the barrier (T4)
#define WAITV(n_) asm volatile("s_waitcnt vmcnt(" #n_ ")" ::: "memory")

// issue one 16B DMA per thread: 8 KB tile ct into ring buf (ct&3)
#define STAGE_B(ct_) gl_lds16(gBsrc + (ct_) * 1024,                        \
                              ldsAll + 32768 + (((ct_) & 3) << 13) + wave * 1024)

// read this wave's 4 B fragments (swizzled) from ring buf (ct&3)
#define LOADBF(ct_) { const unsigned char* pb_ =                           \
        ldsAll + 32768 + (((ct_) & 3) << 13) + bcol * 256;                 \
    bf0 = *((const s16x8*)(pb_ + (((0 * 4 + quad) ^ l15) << 4)));          \
    bf1 = *((const s16x8*)(pb_ + (((1 * 4 + quad) ^ l15) << 4)));          \
    bf2 = *((const s16x8*)(pb_ + (((2 * 4 + quad) ^ l15) << 4)));          \
    bf3 = *((const s16x8*)(pb_ + (((3 * 4 + quad) ^ l15) << 4))); }

#define EPI1(sv, rtvv, lnpv, WVC) {                                        \
    float s_ = (sv);                                                       \
    float u_ = C_K2E * s_;                                                 \
    float arg_ = (s_ > (rtvv)) ? u_ * (tval + s_) : u_;                    \
    float e_ = __builtin_amdgcn_exp2f(arg_);                               \
    if (WVC) { float cz_ = fmaxf(s_, 0.f); e_ = e_ * (cz_ * cz_ + 1.f); }  \
    (lnpv) += e_; }

#define TILE(WVC) {                                                        \
    f32x4 a0_ = (f32x4){0.f, 0.f, 0.f, 0.f};                               \
    f32x4 a1_ = (f32x4){0.f, 0.f, 0.f, 0.f};                               \
    a0_ = MFMA_(af00, bf0, a0_); a1_ = MFMA_(af10, bf0, a1_);              \
    a0_ = MFMA_(af01, bf1, a0_); a1_ = MFMA_(af11, bf1, a1_);              \
    a0_ = MFMA_(af02, bf2, a0_); a1_ = MFMA_(af12, bf2, a1_);              \
    a0_ = MFMA_(af03, bf3, a0_); a1_ = MFMA_(af13, bf3, a1_);              \
    EPI1(a0_[0], rtv00, lnp00, WVC); EPI1(a0_[1], rtv01, lnp01, WVC);      \
    EPI1(a0_[2], rtv02, lnp02, WVC); EPI1(a0_[3], rtv03, lnp03, WVC);      \
    EPI1(a1_[0], rtv10, lnp10, WVC); EPI1(a1_[1], rtv11, lnp11, WVC);      \
    EPI1(a1_[2], rtv12, lnp12, WVC); EPI1(a1_[3], rtv13, lnp13, WVC); }

#define STEP(ct_, WVC) { s16x8 bf0, bf1, bf2, bf3; LOADBF(ct_); TILE(WVC); }

// steady state at top of iter ct: outstanding DMAs = {ct, ct+1, ct+2}.
// WAITV(2) -> B(ct) landed (issued 3 iters ago, ~1200cy cover); barrier ->
// all waves' B(ct) landed AND all done reading tile ct-1, so B(ct+3) may
// overwrite buf((ct+3)&3) == buf((ct-1)&3). Tail peels use vmcnt(2/1/0).
#define RUNLOOP(WVC) {                                                     \
    _Pragma("unroll 1")                                                    \
    for (int ct = 0; ct < 13; ++ct) {                                      \
        WAITV(2);                                                          \
        __builtin_amdgcn_s_barrier();                                      \
        STAGE_B(ct + 3);                                                   \
        STEP(ct, WVC);                                                     \
    }                                                                      \
    WAITV(2); __builtin_amdgcn_s_barrier(); STEP(13, WVC);                 \
    WAITV(1); __builtin_amdgcn_s_barrier(); STEP(14, WVC);                 \
    WAITV(0); __builtin_amdgcn_s_barrier(); STEP(15, WVC); }

#define STORE1(lnpv, mt, r) { float v_ = (lnpv);                           \
    v_ += __shfl_xor(v_, 1); v_ += __shfl_xor(v_, 2);                      \
    v_ += __shfl_xor(v_, 4); v_ += __shfl_xor(v_, 8);                      \
    if (l15 == 0)                                                          \
        lnacc2[slice * N_ROWS + rowbase + wr * 32 + (mt) * 16 + quad * 4 + (r)] = v_; }

__global__ __launch_bounds__(512, 4) void k_passB(const unsigned* __restrict__ f1n,
                                                  const unsigned* __restrict__ f2n,
                                                  const float* __restrict__ rt,
                                                  const float* __restrict__ tw,
                                                  float* __restrict__ lnacc2) {
    __shared__ __align__(16) unsigned char ldsAll[65536];   // A: 0..32K, B ring: 32K..64K
    const int tid = threadIdx.x;
    const int wave = tid >> 6, lane = tid & 63;
    const int wr = wave >> 1, wc = wave & 1;     // wave tile: 32 rows x 256 cols
    const int quad = lane >> 4, l15 = lane & 15;
    const int rowbase = blockIdx.x * 128;
    const float tval = tw[0];
    const bool wv = (tval > C_VALID);

    // stage A tile (128 rows, 32 KB), XOR-swizzled on the global-source side
    {
        const int srow = tid >> 4;                        // 0..31
        const int sq   = (tid & 15) ^ (srow & 15);
        const unsigned* gA = f1n + rowbase * 64 + srow * 64 + sq * 4;
        const int loff = wave * 1024;
        #pragma unroll
        for (int it = 0; it < 4; ++it)
            gl_lds16(gA + it * 2048, ldsAll + loff + it * 8192);
    }

    // per-thread B DMA source (same XOR involution as A, pre-swizzled on global side)
    const int col16 = tid >> 4;
    const int ch    = tid & 15;
    const unsigned* gBsrc = f2n
        + (blockIdx.y * 512 + ((col16 >> 4) << 8) + (col16 & 15)) * 64
        + ((ch ^ (col16 & 15)) << 2);

    STAGE_B(0);   // prime 3 tiles of the ring alongside A
    STAGE_B(1);
    STAGE_B(2);

    const int rbase = rowbase + wr * 32 + quad * 4;
    float rtv00 = rt[rbase + 0],  rtv01 = rt[rbase + 1];
    float rtv02 = rt[rbase + 2],  rtv03 = rt[rbase + 3];
    float rtv10 = rt[rbase + 16], rtv11 = rt[rbase + 17];
    float rtv12 = rt[rbase + 18], rtv13 = rt[rbase + 19];

    __syncthreads();   // full drain: A + B0..B2 resident

    // A fragments for the whole K=128 into named VGPRs (8 x ds_read_b128)
    const unsigned char* pA0 = ldsAll + (wr * 32 + l15) * 256;
    const unsigned char* pA1 = pA0 + 16 * 256;
    s16x8 af00 = *((const s16x8*)(pA0 + (((0 * 4 + quad) ^ l15) << 4)));
    s16x8 af01 = *((const s16x8*)(pA0 + (((1 * 4 + quad) ^ l15) << 4)));
    s16x8 af02 = *((const s16x8*)(pA0 + (((2 * 4 + quad) ^ l15) << 4)));
    s16x8 af03 = *((const s16x8*)(pA0 + (((3 * 4 + quad) ^ l15) << 4)));
    s16x8 af10 = *((const s16x8*)(pA1 + (((0 * 4 + quad) ^ l15) << 4)));
    s16x8 af11 = *((const s16x8*)(pA1 + (((1 * 4 + quad) ^ l15) << 4)));
    s16x8 af12 = *((const s16x8*)(pA1 + (((2 * 4 + quad) ^ l15) << 4)));
    s16x8 af13 = *((const s16x8*)(pA1 + (((3 * 4 + quad) ^ l15) << 4)));

    const int bcol = wc * 16 + l15;    // this wave's column slot in the B LDS tile

    float lnp00 = 0.f, lnp01 = 0.f, lnp02 = 0.f, lnp03 = 0.f;
    float lnp10 = 0.f, lnp11 = 0.f, lnp12 = 0.f, lnp13 = 0.f;

    if (wv) { RUNLOOP(1); } else { RUNLOOP(0); }

    // per-row partial sums: non-atomic slice store (32 slices, fully overwritten)
    const int slice = blockIdx.y * 2 + wc;
    STORE1(lnp00, 0, 0); STORE1(lnp01, 0, 1); STORE1(lnp02, 0, 2); STORE1(lnp03, 0, 3);
    STORE1(lnp10, 1, 0); STORE1(lnp11, 1, 1); STORE1(lnp12, 1, 2); STORE1(lnp13, 1, 3);
}

// ---- K5: positive correction + per-row loss + fused final reduce ----
__global__ void k_lossC(const float* __restrict__ simlist, const int* __restrict__ rowcnt,
                        const float* __restrict__ rt, const float* __restrict__ tw,
                        const float* __restrict__ lnacc2, float* __restrict__ out) {
    int t = threadIdx.x;
    int sub = t >> 3, sl = t & 7;
    int i = blockIdx.x * 32 + sub;
    int cnt = rowcnt[i];
    if (cnt > KMAX) cnt = KMAX;
    float tval = tw[0];
    bool wv = (tval > C_VALID);
    float rti = rt[i];
    float lp = 0.f, den = 0.f;
    for (int e = sl; e < cnt; e += 8) {
        float s = simlist[i * KMAX + e];
        // what k_passB added for this (pos) entry:
        float sh = (s > rti) ? s * (tval + s) : s;
        float en = __builtin_amdgcn_exp2f(C_K2E * sh);
        // true positive contribution:
        float ctm = s * C_COS_M - sqrtf(fmaxf(0.f, 1.f - s * s)) * C_SIN_M;
        float fp = (s > C_THRESH) ? ctm : (s - C_MM);
        float ep = __builtin_amdgcn_exp2f(C_K2E * fp);
        if (wv) {
            float cz = fmaxf(s, 0.f);
            en *= cz * cz + 1.f;
            float d = 1.f - s;
            ep *= d * d + 1.f;
        }
        den -= en;
        lp += ep;
    }
    // dense-pass partials: 32 slices, 4 per lane
    float lnsum = 0.f;
    #pragma unroll
    for (int p = 0; p < 4; ++p) lnsum += lnacc2[(sl + p * 8) * N_ROWS + i];
    #pragma unroll
    for (int k = 1; k < 8; k <<= 1) {
        den += __shfl_xor(den, k);
        lp += __shfl_xor(lp, k);
        lnsum += __shfl_xor(lnsum, k);
    }
    float ln = lnsum + den;
    float rl = (__builtin_amdgcn_logf(lp + ln) - __builtin_amdgcn_logf(lp)) * C_LN2;
    // all 8 sub-lanes hold rl; sum the wave's 8 rows (each counted once)
    rl += __shfl_xor(rl, 8);
    rl += __shfl_xor(rl, 16);
    rl += __shfl_xor(rl, 32);
    __shared__ float sa[4];
    if ((t & 63) == 0) sa[t >> 6] = rl;
    __syncthreads();
    if (t == 0)
        atomicAdd(out, (sa[0] + sa[1] + sa[2] + sa[3]) * (1.0f / (float)N_ROWS));
}

extern "C" void kernel_launch(void* const* d_in, const int* in_sizes, int n_in,
                              void* d_out, int out_size, void* d_ws, size_t ws_size,
                              hipStream_t stream) {
    (void)in_sizes; (void)n_in; (void)out_size; (void)ws_size;
    const float* f1 = (const float*)d_in[0];
    const float* f2 = (const float*)d_in[1];
    const int* labels = (const int*)d_in[2];
    float* out = (float*)d_out;
    char* ws = (char*)d_ws;

    // ws layout (bytes); only hist needs pre-zero (atomic counters)
    unsigned* f1n          = (unsigned*)(ws + 0);              // 2 MB  bf16-packed
    unsigned* f2n          = (unsigned*)(ws + 2097152);        // 2 MB
    float* simlist         = (float*)(ws + 4194304);           // 2 MB (64 sims/row cap)
    float* rt              = (float*)(ws + 6291456);           // 32 KB
    float* row_sim         = (float*)(ws + 6324224);           // 32 KB
    int* rowcnt            = (int*)(ws + 6356992);             // 32 KB
    float* lnacc2          = (float*)(ws + 6389760);           // 1 MB (32 slices x 8192)
    unsigned short* bucket = (unsigned short*)(ws + 7438336);  // 128 KB (1024 x 64 x u16)
    float* tw              = (float*)(ws + 7569408);           // 4 B
    int* hist              = (int*)(ws + 7569472);             // 4 KB  -- zeroed

    hipMemsetAsync(hist, 0, 4096, stream);

    k_norm<<<dim3(4096), dim3(256), 0, stream>>>(f1, f2, labels, f1n, f2n, hist, bucket, out);
    k_passA<<<dim3(2048), dim3(256), 0, stream>>>(f1n, f2n, labels, hist, bucket,
                                                  rt, row_sim, rowcnt, simlist);
    k_finalize<<<dim3(1), dim3(1024), 0, stream>>>(row_sim, hist, tw);
    k_passB<<<dim3(64, 16), dim3(512), 0, stream>>>(f1n, f2n, rt, tw, lnacc2);
    k_lossC<<<dim3(256), dim3(256), 0, stream>>>(simlist, rowcnt, rt, tw, lnacc2, out);
}